// Round 6
// baseline (6283.318 us; speedup 1.0000x reference)
//
#include <hip/hip_runtime.h>
#include <hip/hip_bf16.h>
#include <math.h>

// Problem constants
#define BB 128
#define TT 1024
#define DD 256
#define HH 256
#define MM (BB * TT)
#define NN3 768

typedef __attribute__((ext_vector_type(8))) short short8;
typedef __attribute__((ext_vector_type(4))) float f32x4;
typedef __attribute__((address_space(1))) unsigned int gu32;
typedef __attribute__((address_space(3))) unsigned int lu32;

static __device__ __forceinline__ float bf2f(unsigned int u16) {
    return __uint_as_float(u16 << 16);
}
// RNE
static __device__ __forceinline__ unsigned short f2bf(float f) {
    unsigned int u = __float_as_uint(f);
    unsigned int r = u + 0x7FFFu + ((u >> 16) & 1u);
    return (unsigned short)(r >> 16);
}
// round-half-up, 2 ops (per-step activations)
static __device__ __forceinline__ unsigned int f2bf_fast_u32(float f) {
    return (__float_as_uint(f) + 0x8000u) >> 16;
}

static __device__ __forceinline__ void barrier_lgkm() {
    asm volatile("s_waitcnt lgkmcnt(0)\n\ts_barrier" ::: "memory");
}

// lane^1 exchange, pure VALU (quad_perm [1,0,3,2] = 0xB1). NOT __shfl
// (which emits ds_bpermute and would load the LDS pipe we're relieving).
static __device__ __forceinline__ unsigned int dpp_xor1(unsigned int v) {
    return (unsigned int)__builtin_amdgcn_mov_dpp((int)v, 0xB1, 0xF, 0xF, false);
}

// ---------------------------------------------------------------------------
// Kernel A: transpose+convert W -> Wb[768][256] bf16 (row n = gate*256+col,
// entries along k). One block per n-row.
// ---------------------------------------------------------------------------
__global__ __launch_bounds__(256) void wb_kernel(
    const float* __restrict__ Wz, const float* __restrict__ Wr,
    const float* __restrict__ Wh, unsigned short* __restrict__ Wb)
{
    int n = blockIdx.x;          // 0..767
    int g = n >> 8, col = n & 255;
    const float* W = (g == 0) ? Wz : (g == 1 ? Wr : Wh);
    int k = threadIdx.x;         // 0..255
    Wb[(size_t)n * 256 + k] = f2bf(W[(size_t)k * HH + col]);
}

// ---------------------------------------------------------------------------
// Kernel B: xproj via bf16 MFMA, M-major / batch-fragment layout.
// FROZEN at R5 (three consecutive aux nulls: 386/377/368 us — insensitive
// to occupancy and pipelining edits; no validated theory of its residual).
// ---------------------------------------------------------------------------
__global__ __launch_bounds__(256)
__attribute__((amdgpu_waves_per_eu(2, 2)))
void xproj_mfma(
    const float* __restrict__ x, const unsigned short* __restrict__ Wb,
    const float* __restrict__ bz, const float* __restrict__ br,
    const float* __restrict__ bh, unsigned short* __restrict__ xw)
{
    const int tid  = threadIdx.x;
    const int lane = tid & 63;
    const int wv   = tid >> 6;
    const int nq   = lane & 15;
    const int kq   = lane >> 4;

    const int bid = blockIdx.x >> 7;          // 0..7
    const int t0  = (blockIdx.x & 127) * 8;   // 0..1016
    const int tw0 = t0 + wv * 2;

    short8 af[8][2];
#pragma unroll
    for (int mi = 0; mi < 2; ++mi) {
        const float* xrow = &x[((size_t)(bid * 16 + nq) * 1024 + (tw0 + mi)) * 256];
#pragma unroll
        for (int c = 0; c < 8; ++c) {
            const float* xp = xrow + c * 32 + kq * 8;
            float4 f0 = *(const float4*)xp;
            float4 f1 = *(const float4*)(xp + 4);
            short8 a;
            a[0] = (short)f2bf(f0.x); a[1] = (short)f2bf(f0.y);
            a[2] = (short)f2bf(f0.z); a[3] = (short)f2bf(f0.w);
            a[4] = (short)f2bf(f1.x); a[5] = (short)f2bf(f1.y);
            a[6] = (short)f2bf(f1.z); a[7] = (short)f2bf(f1.w);
            af[c][mi] = a;
        }
    }

    const size_t wbyte = (size_t)nq * 256;   // row offset within a subtile

    auto ldwf = [&](int st, short8* dst) {
#pragma unroll
        for (int c = 0; c < 8; ++c)
            dst[c] = *(const short8*)&Wb[(size_t)st * 4096 + wbyte
                                         + c * 32 + kq * 8];
    };

    auto do_subtile = [&](int st, const short8* wf) {
        const float* bias = (st < 16) ? bz : (st < 32 ? br : bh);
        const float bv = bias[(st & 15) * 16 + nq];

        f32x4 acc0 = (f32x4){0.f, 0.f, 0.f, 0.f};
        f32x4 acc1 = (f32x4){0.f, 0.f, 0.f, 0.f};
#pragma unroll
        for (int c = 0; c < 8; ++c) {
            acc0 = __builtin_amdgcn_mfma_f32_16x16x32_bf16(af[c][0], wf[c], acc0, 0, 0, 0);
            acc1 = __builtin_amdgcn_mfma_f32_16x16x32_bf16(af[c][1], wf[c], acc1, 0, 0, 0);
        }

#pragma unroll
        for (int mi = 0; mi < 2; ++mi) {
            f32x4 a = (mi == 0) ? acc0 : acc1;
            unsigned int lo = (unsigned int)f2bf(a[0] + bv)
                            | ((unsigned int)f2bf(a[1] + bv) << 16);
            unsigned int hi = (unsigned int)f2bf(a[2] + bv)
                            | ((unsigned int)f2bf(a[3] + bv) << 16);
            uint2 val; val.x = lo; val.y = hi;
            *(uint2*)&xw[(size_t)((tw0 + mi) * 8 + bid) * 12288
                         + st * 256 + kq * 64 + nq * 4] = val;
        }
    };

    short8 wfA[8], wfB[8];
    ldwf(0, wfA);
#pragma unroll 1
    for (int sp = 0; sp < 24; ++sp) {
        const int e = sp * 2;
        ldwf(e + 1, wfB);
        do_subtile(e, wfA);
        ldwf(e + 2 < 48 ? e + 2 : 47, wfA);
        do_subtile(e + 1, wfB);
    }
}

// ---------------------------------------------------------------------------
// Kernel C: persistent-register MFMA GRU recurrence.
// R6: ONE change vs the verified R4/R5 version — epilogue LDS writes packed
// b16 -> b32. Theory: the 1024 conflict-cy/step (= counter exactly, incl.
// wave-count proportionality R0 2^22 vs R1+ 2^23) comes from lane pairs
// (nq, nq^1) writing two halves of the SAME dword as separate b16 stores.
// Fix: quad-perm DPP (VALU) exchanges the partner's bf16; even-nq lanes
// store one b32 covering both cols. 32 lanes -> 2-way bank alias (free).
// MFMA chains / barriers / loads byte-identical (R2 lesson).
// ---------------------------------------------------------------------------
__global__ __launch_bounds__(1024)
__attribute__((amdgpu_waves_per_eu(4, 4)))
void gru_rec_kernel(
    const unsigned short* __restrict__ xw,
    const float* __restrict__ Uz, const float* __restrict__ Ur,
    const float* __restrict__ Uh,
    float* __restrict__ out)
{
    __shared__ short hA[16][264];    // h bf16, stride 132 dw
    __shared__ short rhA[16][264];   // r*h bf16

    const int tid  = threadIdx.x;
    const int lane = tid & 63;
    const int wv   = tid >> 6;       // 0..15
    const int nq   = lane & 15;
    const int kq   = lane >> 4;
    const int bid  = blockIdx.x;
    const int col0 = wv * 16;        // this wave's 16-column tile

    // dword index within a row, for the packed (2-col) epilogue stores
    const int dwcol = (col0 + nq) >> 1;   // even-nq lanes store here
    const bool wlane = ((nq & 1) == 0);

    // ---- persistent weight fragments: 3 gates x 8 k-chunks = 96 regs/lane ----
    short8 wz[8], wr[8], whv[8];
#pragma unroll
    for (int c = 0; c < 8; ++c) {
        short8 fz, fr, fh;
#pragma unroll
        for (int j = 0; j < 8; ++j) {
            size_t rowoff = (size_t)(c * 32 + kq * 8 + j) * HH + col0 + nq;
            fz[j] = (short)f2bf(Uz[rowoff]);
            fr[j] = (short)f2bf(Ur[rowoff]);
            fh[j] = (short)f2bf(Uh[rowoff]);
        }
        wz[c] = fz; wr[c] = fr; whv[c] = fh;
    }

    for (int idx = tid; idx < 16 * 264; idx += 1024) ((short*)hA)[idx] = 0;
    float hprev[4];
#pragma unroll
    for (int i = 0; i < 4; ++i) hprev[i] = 0.f;

    // per-lane xw source: 3 uint2 per step (z, r, h inits), coalesced
    // 512 B per wave. Step stride = 8*12288 shorts.
    const unsigned short* xlane =
        xw + (size_t)bid * 12288 + (size_t)(wv * 64 + lane) * 4;

    uint2 xb0[3], xb1[3];   // named double buffers (compile-time indexed)
    auto ldx = [&](int t, uint2* dst) {
        const unsigned short* p = xlane + (size_t)t * (8 * 12288);
        dst[0] = *(const uint2*)(p);
        dst[1] = *(const uint2*)(p + 4096);
        dst[2] = *(const uint2*)(p + 8192);
    };
    ldx(0, xb0);

    barrier_lgkm();   // hA zero-fill visibility

    auto step = [&](int t, int par) {
        uint2* cur = par ? xb1 : xb0;
        uint2* nxt = par ? xb0 : xb1;
        int tn = (t + 1 < TT) ? (t + 1) : (TT - 1);
        ldx(tn, nxt);   // prefetch next step's x into the other buffer

        // ---- phase A: acc init = x (z,r), then MFMA chains over h ----
        f32x4 accZ, accR;
        {
            uint2 uz = cur[0];
            uint2 ur = cur[1];
            accZ[0] = bf2f(uz.x & 0xffffu);
            accZ[1] = bf2f(uz.x >> 16);
            accZ[2] = bf2f(uz.y & 0xffffu);
            accZ[3] = bf2f(uz.y >> 16);
            accR[0] = bf2f(ur.x & 0xffffu);
            accR[1] = bf2f(ur.x >> 16);
            accR[2] = bf2f(ur.y & 0xffffu);
            accR[3] = bf2f(ur.y >> 16);
        }
#pragma unroll
        for (int c = 0; c < 8; ++c) {
            short8 af = *(const short8*)&hA[nq][c * 32 + kq * 8];
            accZ = __builtin_amdgcn_mfma_f32_16x16x32_bf16(af, wz[c], accZ, 0, 0, 0);
            accR = __builtin_amdgcn_mfma_f32_16x16x32_bf16(af, wr[c], accR, 0, 0, 0);
        }

        // r epilogue only (z deferred to phase B; accZ stays live)
        // packed b32 stores: even-nq lane writes (own | partner<<16)
        {
            unsigned int rh[4];
#pragma unroll
            for (int i = 0; i < 4; ++i) {
                float r = __builtin_amdgcn_fmed3f(
                    __builtin_fmaf(0.2f, accR[i], 0.5f), 0.f, 1.f);
                rh[i] = f2bf_fast_u32(r * hprev[i]);
            }
            unsigned int pp[4];
#pragma unroll
            for (int i = 0; i < 4; ++i) pp[i] = dpp_xor1(rh[i]);
            if (wlane) {
#pragma unroll
                for (int i = 0; i < 4; ++i)
                    ((lu32*)&rhA[kq * 4 + i][0])[dwcol] = rh[i] | (pp[i] << 16);
            }
        }
        barrier_lgkm();

        // ---- phase B: accH init = xh, MFMA over r*h, z + h epilogue ----
        f32x4 accH;
        {
            uint2 u = cur[2];
            accH[0] = bf2f(u.x & 0xffffu);
            accH[1] = bf2f(u.x >> 16);
            accH[2] = bf2f(u.y & 0xffffu);
            accH[3] = bf2f(u.y >> 16);
        }
#pragma unroll
        for (int c = 0; c < 8; ++c) {
            short8 af = *(const short8*)&rhA[nq][c * 32 + kq * 8];
            accH = __builtin_amdgcn_mfma_f32_16x16x32_bf16(af, whv[c], accH, 0, 0, 0);
        }

        {
            unsigned int hv[4];
#pragma unroll
            for (int i = 0; i < 4; ++i) {
                float z = __builtin_amdgcn_fmed3f(
                    __builtin_fmaf(0.2f, accZ[i], 0.5f), 0.f, 1.f);
                float a = __builtin_amdgcn_fmed3f(accH[i], -12.f, 12.f);
                float e  = exp2f(a * 2.88539008f);          // e^(2a)
                float hh = __builtin_fmaf(-2.f, __builtin_amdgcn_rcpf(e + 1.f), 1.f);
                float hn = __builtin_fmaf(z, hprev[i] - hh, hh);
                hprev[i] = hn;
                hv[i] = f2bf_fast_u32(hn);
            }
            unsigned int pp[4];
#pragma unroll
            for (int i = 0; i < 4; ++i) pp[i] = dpp_xor1(hv[i]);
            if (wlane) {
#pragma unroll
                for (int i = 0; i < 4; ++i)
                    ((lu32*)&hA[kq * 4 + i][0])[dwcol] = hv[i] | (pp[i] << 16);
            }
        }
        barrier_lgkm();
    };

    for (int t = 0; t < TT; t += 2) {
        step(t, 0);
        step(t + 1, 1);
    }

#pragma unroll
    for (int i = 0; i < 4; ++i)
        out[(size_t)(bid * 16 + kq * 4 + i) * HH + col0 + nq] = hprev[i];
}

// ---------------------------------------------------------------------------
extern "C" void kernel_launch(void* const* d_in, const int* in_sizes, int n_in,
                              void* d_out, int out_size, void* d_ws, size_t ws_size,
                              hipStream_t stream) {
    const float* x  = (const float*)d_in[0];
    const float* Wz = (const float*)d_in[1];
    const float* Wr = (const float*)d_in[2];
    const float* Wh = (const float*)d_in[3];
    const float* Uz = (const float*)d_in[4];
    const float* Ur = (const float*)d_in[5];
    const float* Uh = (const float*)d_in[6];
    const float* bz = (const float*)d_in[7];
    const float* br = (const float*)d_in[8];
    const float* bh = (const float*)d_in[9];
    float* out = (float*)d_out;

    // workspace: [xw: 192 MiB bf16][Wb: 768*256 bf16 = 384 KiB]
    unsigned short* xw = (unsigned short*)d_ws;
    unsigned short* Wb =
        (unsigned short*)((char*)d_ws + (size_t)MM * NN3 * sizeof(unsigned short));

    wb_kernel<<<NN3, 256, 0, stream>>>(Wz, Wr, Wh, Wb);

    // 1024 blocks: 8 bid-groups x 128 t-chunks of 8 timesteps
    xproj_mfma<<<1024, 256, 0, stream>>>(x, Wb, bz, br, bh, xw);

    gru_rec_kernel<<<8, 1024, 0, stream>>>(xw, Uz, Ur, Uh, out);
}

// Round 7
// 2497.641 us; speedup vs baseline: 2.5157x; 2.5157x over previous
//
#include <hip/hip_runtime.h>
#include <hip/hip_bf16.h>
#include <math.h>

// Problem constants
#define BB 128
#define TT 1024
#define DD 256
#define HH 256
#define MM (BB * TT)
#define NN3 768

typedef __attribute__((ext_vector_type(8))) short short8;
typedef __attribute__((ext_vector_type(4))) float f32x4;
typedef __attribute__((address_space(1))) unsigned int gu32;
typedef __attribute__((address_space(3))) unsigned int lu32;

static __device__ __forceinline__ float bf2f(unsigned int u16) {
    return __uint_as_float(u16 << 16);
}
// RNE
static __device__ __forceinline__ unsigned short f2bf(float f) {
    unsigned int u = __float_as_uint(f);
    unsigned int r = u + 0x7FFFu + ((u >> 16) & 1u);
    return (unsigned short)(r >> 16);
}
// round-half-up, 2 ops (per-step activations)
static __device__ __forceinline__ unsigned short f2bf_fast(float f) {
    return (unsigned short)((__float_as_uint(f) + 0x8000u) >> 16);
}

static __device__ __forceinline__ void barrier_lgkm() {
    asm volatile("s_waitcnt lgkmcnt(0)\n\ts_barrier" ::: "memory");
}

// ---------------------------------------------------------------------------
// Kernel A: transpose+convert W -> Wb[768][256] bf16 (row n = gate*256+col,
// entries along k). One block per n-row.
// ---------------------------------------------------------------------------
__global__ __launch_bounds__(256) void wb_kernel(
    const float* __restrict__ Wz, const float* __restrict__ Wr,
    const float* __restrict__ Wh, unsigned short* __restrict__ Wb)
{
    int n = blockIdx.x;          // 0..767
    int g = n >> 8, col = n & 255;
    const float* W = (g == 0) ? Wz : (g == 1 ? Wr : Wh);
    int k = threadIdx.x;         // 0..255
    Wb[(size_t)n * 256 + k] = f2bf(W[(size_t)k * HH + col]);
}

// ---------------------------------------------------------------------------
// Kernel B: xproj via bf16 MFMA, M-major / batch-fragment layout.
// FROZEN at R5 (three consecutive aux nulls — insensitive to occupancy and
// pipelining edits).
// ---------------------------------------------------------------------------
__global__ __launch_bounds__(256)
__attribute__((amdgpu_waves_per_eu(2, 2)))
void xproj_mfma(
    const float* __restrict__ x, const unsigned short* __restrict__ Wb,
    const float* __restrict__ bz, const float* __restrict__ br,
    const float* __restrict__ bh, unsigned short* __restrict__ xw)
{
    const int tid  = threadIdx.x;
    const int lane = tid & 63;
    const int wv   = tid >> 6;
    const int nq   = lane & 15;
    const int kq   = lane >> 4;

    const int bid = blockIdx.x >> 7;          // 0..7
    const int t0  = (blockIdx.x & 127) * 8;   // 0..1016
    const int tw0 = t0 + wv * 2;

    short8 af[8][2];
#pragma unroll
    for (int mi = 0; mi < 2; ++mi) {
        const float* xrow = &x[((size_t)(bid * 16 + nq) * 1024 + (tw0 + mi)) * 256];
#pragma unroll
        for (int c = 0; c < 8; ++c) {
            const float* xp = xrow + c * 32 + kq * 8;
            float4 f0 = *(const float4*)xp;
            float4 f1 = *(const float4*)(xp + 4);
            short8 a;
            a[0] = (short)f2bf(f0.x); a[1] = (short)f2bf(f0.y);
            a[2] = (short)f2bf(f0.z); a[3] = (short)f2bf(f0.w);
            a[4] = (short)f2bf(f1.x); a[5] = (short)f2bf(f1.y);
            a[6] = (short)f2bf(f1.z); a[7] = (short)f2bf(f1.w);
            af[c][mi] = a;
        }
    }

    const size_t wbyte = (size_t)nq * 256;   // row offset within a subtile

    auto ldwf = [&](int st, short8* dst) {
#pragma unroll
        for (int c = 0; c < 8; ++c)
            dst[c] = *(const short8*)&Wb[(size_t)st * 4096 + wbyte
                                         + c * 32 + kq * 8];
    };

    auto do_subtile = [&](int st, const short8* wf) {
        const float* bias = (st < 16) ? bz : (st < 32 ? br : bh);
        const float bv = bias[(st & 15) * 16 + nq];

        f32x4 acc0 = (f32x4){0.f, 0.f, 0.f, 0.f};
        f32x4 acc1 = (f32x4){0.f, 0.f, 0.f, 0.f};
#pragma unroll
        for (int c = 0; c < 8; ++c) {
            acc0 = __builtin_amdgcn_mfma_f32_16x16x32_bf16(af[c][0], wf[c], acc0, 0, 0, 0);
            acc1 = __builtin_amdgcn_mfma_f32_16x16x32_bf16(af[c][1], wf[c], acc1, 0, 0, 0);
        }

#pragma unroll
        for (int mi = 0; mi < 2; ++mi) {
            f32x4 a = (mi == 0) ? acc0 : acc1;
            unsigned int lo = (unsigned int)f2bf(a[0] + bv)
                            | ((unsigned int)f2bf(a[1] + bv) << 16);
            unsigned int hi = (unsigned int)f2bf(a[2] + bv)
                            | ((unsigned int)f2bf(a[3] + bv) << 16);
            uint2 val; val.x = lo; val.y = hi;
            *(uint2*)&xw[(size_t)((tw0 + mi) * 8 + bid) * 12288
                         + st * 256 + kq * 64 + nq * 4] = val;
        }
    };

    short8 wfA[8], wfB[8];
    ldwf(0, wfA);
#pragma unroll 1
    for (int sp = 0; sp < 24; ++sp) {
        const int e = sp * 2;
        ldwf(e + 1, wfB);
        do_subtile(e, wfA);
        ldwf(e + 2 < 48 ? e + 2 : 47, wfA);
        do_subtile(e + 1, wfB);
    }
}

// ---------------------------------------------------------------------------
// Kernel C: persistent-register MFMA GRU recurrence.
// EXACT REVERT to the R4/R5-verified 2117/2135-us version. R6's write-packing
// experiment regressed 2.8x but proved the decisive fact: SQ_LDS_BANK_CONFLICT
// (exactly 2^23) is unchanged under complete epilogue-write restructuring —
// it is structural accounting of the 256 wave64 ds_read_b128/step (4 counted
// cycles per b128 read), not a fixable hazard. The LDS read floor (~4860
// cy/step) is real for this decomposition; all alternatives measured worse
// or register-walled (R0 8-wave 5540, parity split 6520, LDS-bypass null,
// write-pack refuted). Do not touch.
// ---------------------------------------------------------------------------
__global__ __launch_bounds__(1024)
__attribute__((amdgpu_waves_per_eu(4, 4)))
void gru_rec_kernel(
    const unsigned short* __restrict__ xw,
    const float* __restrict__ Uz, const float* __restrict__ Ur,
    const float* __restrict__ Uh,
    float* __restrict__ out)
{
    __shared__ short hA[16][264];    // h bf16, stride 132 dw
    __shared__ short rhA[16][264];   // r*h bf16

    const int tid  = threadIdx.x;
    const int lane = tid & 63;
    const int wv   = tid >> 6;       // 0..15
    const int nq   = lane & 15;
    const int kq   = lane >> 4;
    const int bid  = blockIdx.x;
    const int col0 = wv * 16;        // this wave's 16-column tile

    // ---- persistent weight fragments: 3 gates x 8 k-chunks = 96 regs/lane ----
    short8 wz[8], wr[8], whv[8];
#pragma unroll
    for (int c = 0; c < 8; ++c) {
        short8 fz, fr, fh;
#pragma unroll
        for (int j = 0; j < 8; ++j) {
            size_t rowoff = (size_t)(c * 32 + kq * 8 + j) * HH + col0 + nq;
            fz[j] = (short)f2bf(Uz[rowoff]);
            fr[j] = (short)f2bf(Ur[rowoff]);
            fh[j] = (short)f2bf(Uh[rowoff]);
        }
        wz[c] = fz; wr[c] = fr; whv[c] = fh;
    }

    for (int idx = tid; idx < 16 * 264; idx += 1024) ((short*)hA)[idx] = 0;
    float hprev[4];
#pragma unroll
    for (int i = 0; i < 4; ++i) hprev[i] = 0.f;

    // per-lane xw source: 3 uint2 per step (z, r, h inits), coalesced
    // 512 B per wave. Step stride = 8*12288 shorts.
    const unsigned short* xlane =
        xw + (size_t)bid * 12288 + (size_t)(wv * 64 + lane) * 4;

    uint2 xb0[3], xb1[3];   // named double buffers (compile-time indexed)
    auto ldx = [&](int t, uint2* dst) {
        const unsigned short* p = xlane + (size_t)t * (8 * 12288);
        dst[0] = *(const uint2*)(p);
        dst[1] = *(const uint2*)(p + 4096);
        dst[2] = *(const uint2*)(p + 8192);
    };
    ldx(0, xb0);

    barrier_lgkm();   // hA zero-fill visibility

    auto step = [&](int t, int par) {
        uint2* cur = par ? xb1 : xb0;
        uint2* nxt = par ? xb0 : xb1;
        int tn = (t + 1 < TT) ? (t + 1) : (TT - 1);
        ldx(tn, nxt);   // prefetch next step's x into the other buffer

        // ---- phase A: acc init = x (z,r), then MFMA chains over h ----
        f32x4 accZ, accR;
        {
            uint2 uz = cur[0];
            uint2 ur = cur[1];
            accZ[0] = bf2f(uz.x & 0xffffu);
            accZ[1] = bf2f(uz.x >> 16);
            accZ[2] = bf2f(uz.y & 0xffffu);
            accZ[3] = bf2f(uz.y >> 16);
            accR[0] = bf2f(ur.x & 0xffffu);
            accR[1] = bf2f(ur.x >> 16);
            accR[2] = bf2f(ur.y & 0xffffu);
            accR[3] = bf2f(ur.y >> 16);
        }
#pragma unroll
        for (int c = 0; c < 8; ++c) {
            short8 af = *(const short8*)&hA[nq][c * 32 + kq * 8];
            accZ = __builtin_amdgcn_mfma_f32_16x16x32_bf16(af, wz[c], accZ, 0, 0, 0);
            accR = __builtin_amdgcn_mfma_f32_16x16x32_bf16(af, wr[c], accR, 0, 0, 0);
        }

        // r epilogue only (z deferred to phase B; accZ stays live)
#pragma unroll
        for (int i = 0; i < 4; ++i) {
            float r = __builtin_amdgcn_fmed3f(
                __builtin_fmaf(0.2f, accR[i], 0.5f), 0.f, 1.f);
            rhA[kq * 4 + i][col0 + nq] = (short)f2bf_fast(r * hprev[i]);
        }
        barrier_lgkm();

        // ---- phase B: accH init = xh, MFMA over r*h, z + h epilogue ----
        f32x4 accH;
        {
            uint2 u = cur[2];
            accH[0] = bf2f(u.x & 0xffffu);
            accH[1] = bf2f(u.x >> 16);
            accH[2] = bf2f(u.y & 0xffffu);
            accH[3] = bf2f(u.y >> 16);
        }
#pragma unroll
        for (int c = 0; c < 8; ++c) {
            short8 af = *(const short8*)&rhA[nq][c * 32 + kq * 8];
            accH = __builtin_amdgcn_mfma_f32_16x16x32_bf16(af, whv[c], accH, 0, 0, 0);
        }

#pragma unroll
        for (int i = 0; i < 4; ++i) {
            float z = __builtin_amdgcn_fmed3f(
                __builtin_fmaf(0.2f, accZ[i], 0.5f), 0.f, 1.f);
            float a = __builtin_amdgcn_fmed3f(accH[i], -12.f, 12.f);
            float e  = exp2f(a * 2.88539008f);          // e^(2a)
            float hh = __builtin_fmaf(-2.f, __builtin_amdgcn_rcpf(e + 1.f), 1.f);
            float hn = __builtin_fmaf(z, hprev[i] - hh, hh);
            hprev[i] = hn;
            hA[kq * 4 + i][col0 + nq] = (short)f2bf_fast(hn);
        }
        barrier_lgkm();
    };

    for (int t = 0; t < TT; t += 2) {
        step(t, 0);
        step(t + 1, 1);
    }

#pragma unroll
    for (int i = 0; i < 4; ++i)
        out[(size_t)(bid * 16 + kq * 4 + i) * HH + col0 + nq] = hprev[i];
}

// ---------------------------------------------------------------------------
extern "C" void kernel_launch(void* const* d_in, const int* in_sizes, int n_in,
                              void* d_out, int out_size, void* d_ws, size_t ws_size,
                              hipStream_t stream) {
    const float* x  = (const float*)d_in[0];
    const float* Wz = (const float*)d_in[1];
    const float* Wr = (const float*)d_in[2];
    const float* Wh = (const float*)d_in[3];
    const float* Uz = (const float*)d_in[4];
    const float* Ur = (const float*)d_in[5];
    const float* Uh = (const float*)d_in[6];
    const float* bz = (const float*)d_in[7];
    const float* br = (const float*)d_in[8];
    const float* bh = (const float*)d_in[9];
    float* out = (float*)d_out;

    // workspace: [xw: 192 MiB bf16][Wb: 768*256 bf16 = 384 KiB]
    unsigned short* xw = (unsigned short*)d_ws;
    unsigned short* Wb =
        (unsigned short*)((char*)d_ws + (size_t)MM * NN3 * sizeof(unsigned short));

    wb_kernel<<<NN3, 256, 0, stream>>>(Wz, Wr, Wh, Wb);

    // 1024 blocks: 8 bid-groups x 128 t-chunks of 8 timesteps
    xproj_mfma<<<1024, 256, 0, stream>>>(x, Wb, bz, br, bh, xw);

    gru_rec_kernel<<<8, 1024, 0, stream>>>(xw, Uz, Ur, Uh, out);
}